// Round 3
// baseline (798.963 us; speedup 1.0000x reference)
//
#include <hip/hip_runtime.h>
#include <hip/hip_fp16.h>

#define T_STEPS 2048
#define BATCH   256
constexpr int NROWS = BATCH * T_STEPS;  // 524288

// ---------- fast math ----------
__device__ __forceinline__ float fexp2(float x) {
#if __has_builtin(__builtin_amdgcn_exp2f)
  return __builtin_amdgcn_exp2f(x);
#else
  return exp2f(x);
#endif
}
__device__ __forceinline__ float frcp(float x) {
#if __has_builtin(__builtin_amdgcn_rcpf)
  return __builtin_amdgcn_rcpf(x);
#else
  return 1.0f / x;
#endif
}

// DPP cross-lane move (codes validated by the passing round-2 kernel)
template<int CTRL>
__device__ __forceinline__ float dppf(float x) {
  int i = __float_as_int(x);
  int r = __builtin_amdgcn_update_dpp(i, i, CTRL, 0xF, 0xF, false);
  return __int_as_float(r);
}
#define DPP_X1  0xB1   // quad_perm {1,0,3,2}: lane^1  (pair partner)
#define DPP_QX2 0x4E   // quad_perm {2,3,0,1}: lane^2  -> value-index u^1
#define DPP_HM  0x141  // row_half_mirror:     lane^7  -> u^3
#define DPP_RM  0x140  // row_mirror:          lane^15 -> u^7

// ---------- Phase 1: ZX[b][t][unit][gate] = x@Wx + b  (fp16) ----------
// lane j (0..31) owns Wx column j; half-wave r handles one row per iter.
__global__ __launch_bounds__(256, 4) void zx_kernel(const float* __restrict__ x,
                                                    const float* __restrict__ Wx,
                                                    const float* __restrict__ bias,
                                                    __half* __restrict__ zx) {
  int wave = (blockIdx.x * 256 + (int)threadIdx.x) >> 6;  // 0..8191
  int lane = (int)threadIdx.x & 63;
  int j    = lane & 31;              // output column (= gate*8 + unit)
  int r    = lane >> 5;

  float wxc[32];
#pragma unroll
  for (int d = 0; d < 32; ++d) wxc[d] = Wx[d * 32 + j];
  float bj = bias[j];

  int st   = ((j & 7) << 2) + (j >> 3);  // permuted: unit*4 + gate
  int base = wave * 64;                  // 64 rows per wave

  for (int it = 0; it < 32; ++it) {
    int row = base + (it << 1) + r;
    const float4* xr = (const float4*)(x + (size_t)row * 32);
    float a = bj, b2 = 0.0f;
#pragma unroll
    for (int qq = 0; qq < 8; ++qq) {
      float4 v = xr[qq];
      a  = fmaf(v.x, wxc[4*qq+0], a);
      b2 = fmaf(v.y, wxc[4*qq+1], b2);
      a  = fmaf(v.z, wxc[4*qq+2], a);
      b2 = fmaf(v.w, wxc[4*qq+3], b2);
    }
    zx[(size_t)row * 32 + st] = __float2half(a + b2);
  }
}

// ---------- Phase 2: recurrence, 16 lanes per batch ----------
// lane q = u*2 + p : unit u (0..7), gate-pair p (p=0 -> gates i,f ; p=1 -> g,o).
// Each 16-lane batch group is one DPP row; h replicated on the p-pair.
__global__ __launch_bounds__(64, 1) void lstm_kernel(const __half* __restrict__ zx,
                                                     const float* __restrict__ h0,
                                                     const float* __restrict__ c0,
                                                     const float* __restrict__ Wh,
                                                     float* __restrict__ out) {
  int lane = (int)threadIdx.x;            // 0..63
  int b = blockIdx.x * 4 + (lane >> 4);   // 4 batches per wave
  int q = lane & 15;
  int u = q >> 1;
  int p = q & 1;
  bool pb = (p != 0);

  // weights pre-permuted so rr[m] pairs with h[u^m]
  float wA[8], wB[8];
#pragma unroll
  for (int m = 0; m < 8; ++m) {
    int jrow = u ^ m;
    wA[m] = Wh[jrow * 32 + (2 * p) * 8 + u];
    wB[m] = Wh[jrow * 32 + (2 * p + 1) * 8 + u];
  }
  const float L2E = 1.442695040888963f;
  // slot A activation: sigmoid (p=0, gate i) or tanh (p=1, gate g)
  float cA = pb ? -2.0f * L2E : -L2E;
  float aA = pb ? 2.0f : 1.0f;
  float bA = pb ? -1.0f : 0.0f;

  float h = h0[b * 8 + u];
  float c = c0[b * 8 + u];

  const unsigned* zp = (const unsigned*)zx;            // dword view, 16/row
  size_t zbase = (size_t)b * T_STEPS * 16 + u * 2 + p; // lane's dword in row
  float* op = out + (size_t)b * T_STEPS * 8 + u;

  constexpr int PD = 8;  // prefetch ring (statically indexed)
  unsigned buf[PD];
#pragma unroll
  for (int pp = 0; pp < PD; ++pp) buf[pp] = zp[zbase + (size_t)pp * 16];

  for (int tb = 0; tb < T_STEPS; tb += PD) {
#pragma unroll
    for (int pp = 0; pp < PD; ++pp) {
      __half2 zh = *(const __half2*)&buf[pp];
      float2 zf = __half22float2(zh);   // .x = gate 2p, .y = gate 2p+1
      int tn = tb + PD + pp;
      if (tn < T_STEPS) buf[pp] = zp[zbase + (size_t)tn * 16];

      // allgather h[0..7] within the 16-lane row (7 DPP, depth 3)
      float r0 = h;                    // u
      float r1 = dppf<DPP_QX2>(r0);    // u^1
      float r3 = dppf<DPP_HM >(r0);    // u^3
      float r2 = dppf<DPP_QX2>(r3);    // u^2
      float r7 = dppf<DPP_RM >(r0);    // u^7
      float r6 = dppf<DPP_QX2>(r7);    // u^6
      float r4 = dppf<DPP_HM >(r7);    // u^4
      float r5 = dppf<DPP_QX2>(r4);    // u^5
      float rr[8] = {r0, r1, r2, r3, r4, r5, r6, r7};

      // two 8-term dots, 2 chains each
      float A0 = fmaf(rr[0], wA[0], zf.x), A1 = rr[1] * wA[1];
      float B0 = fmaf(rr[0], wB[0], zf.y), B1 = rr[1] * wB[1];
#pragma unroll
      for (int m = 2; m < 8; m += 2) {
        A0 = fmaf(rr[m],     wA[m],     A0);
        A1 = fmaf(rr[m + 1], wA[m + 1], A1);
        B0 = fmaf(rr[m],     wB[m],     B0);
        B1 = fmaf(rr[m + 1], wB[m + 1], B1);
      }
      float A = A0 + A1, B = B0 + B1;

      // uniform-stream activations
      float eA = fexp2(cA * A);
      float sA = frcp(1.0f + eA);
      float Aact = fmaf(aA, sA, bA);     // i (p=0) or g (p=1)
      float eB = fexp2(-L2E * B);
      float Bact = frcp(1.0f + eB);      // f (p=0) or o (p=1)

      // pair exchange
      float A2 = dppf<DPP_X1>(Aact);
      float B2 = dppf<DPP_X1>(Bact);

      float iv = pb ? A2   : Aact;
      float fv = pb ? B2   : Bact;
      float gv = pb ? Aact : A2;
      float ov = pb ? Bact : B2;

      c = fmaf(fv, c, iv * gv);
      float ec = fexp2(-2.0f * L2E * c);
      float th = fmaf(2.0f, frcp(1.0f + ec), -1.0f);
      h = ov * th;

      op[(size_t)(tb + pp) * 8] = h;   // p-pair writes same addr/data (benign)
    }
  }
  out[(size_t)BATCH * T_STEPS * 8 +             b * 8 + u] = h;
  out[(size_t)BATCH * T_STEPS * 8 + BATCH * 8 + b * 8 + u] = c;
}

extern "C" void kernel_launch(void* const* d_in, const int* in_sizes, int n_in,
                              void* d_out, int out_size, void* d_ws, size_t ws_size,
                              hipStream_t stream) {
  const float* x    = (const float*)d_in[0];
  const float* h0   = (const float*)d_in[1];
  const float* c0   = (const float*)d_in[2];
  const float* Wx   = (const float*)d_in[3];
  const float* Wh   = (const float*)d_in[4];
  const float* bias = (const float*)d_in[5];
  float* out = (float*)d_out;
  __half* zx = (__half*)d_ws;  // 32 MB scratch

  zx_kernel<<<2048, 256, 0, stream>>>(x, Wx, bias, zx);       // 8192 waves x 64 rows
  lstm_kernel<<<BATCH / 4, 64, 0, stream>>>(zx, h0, c0, Wh, out);  // 64 waves
}

// Round 4
// 485.078 us; speedup vs baseline: 1.6471x; 1.6471x over previous
//
#include <hip/hip_runtime.h>
#include <hip/hip_fp16.h>

#define T_STEPS 2048
#define BATCH   256

// ---------- fast math ----------
__device__ __forceinline__ float fexp2(float x) {
#if __has_builtin(__builtin_amdgcn_exp2f)
  return __builtin_amdgcn_exp2f(x);
#else
  return exp2f(x);
#endif
}
__device__ __forceinline__ float frcp(float x) {
#if __has_builtin(__builtin_amdgcn_rcpf)
  return __builtin_amdgcn_rcpf(x);
#else
  return 1.0f / x;
#endif
}

// DPP cross-lane move (codes validated by the passing round-2 kernel)
template<int CTRL>
__device__ __forceinline__ float dppf(float x) {
  int i = __float_as_int(x);
  int r = __builtin_amdgcn_update_dpp(i, i, CTRL, 0xF, 0xF, false);
  return __int_as_float(r);
}
#define DPP_X1   0xB1   // quad_perm {1,0,3,2}: lane^1
#define DPP_X2   0x4E   // quad_perm {2,3,0,1}: lane^2
#define DPP_MIR8 0x141  // row_half_mirror:     lane^7

// pin a float in a VGPR: result of opaque asm is NOT rematerializable,
// so the allocator cannot re-load it from memory inside the loop.
#define PIN(x) asm volatile("" : "+v"(x))

struct half4 { __half2 lo, hi; };  // 8 bytes

// ---------- Phase 1: ZX[b][t][unit*4+gate] = x@Wx + b  (fp16, packed stores) ----------
// lane l (0..31) owns PERMUTED position l  ->  original col j = (l&3)*8 + (l>>2).
// Pair (l, l^1) = (gate g, g^1) of one unit -> exchange via DPP xor1, pack dword.
__global__ __launch_bounds__(256, 4) void zx_kernel(const float* __restrict__ x,
                                                    const float* __restrict__ Wx,
                                                    const float* __restrict__ bias,
                                                    unsigned* __restrict__ zx) {
  int wave = (blockIdx.x * 256 + (int)threadIdx.x) >> 6;  // 0..8191
  int lane = (int)threadIdx.x & 63;
  int l    = lane & 31;
  int r    = lane >> 5;
  int j    = (l & 3) * 8 + (l >> 2);

  float wxc[32];
#pragma unroll
  for (int d = 0; d < 32; ++d) wxc[d] = Wx[d * 32 + j];
  float bj = bias[j];
#pragma unroll
  for (int d = 0; d < 32; ++d) PIN(wxc[d]);
  PIN(bj);

  int base = wave * 64;  // 64 rows per wave, 2 per iter (one per half-wave)

  for (int it = 0; it < 32; ++it) {
    int row = base + (it << 1) + r;
    const float4* xr = (const float4*)(x + (size_t)row * 32);
    float a = bj, b2 = 0.0f;
#pragma unroll
    for (int qq = 0; qq < 8; ++qq) {
      float4 v = xr[qq];
      a  = fmaf(v.x, wxc[4*qq+0], a);
      b2 = fmaf(v.y, wxc[4*qq+1], b2);
      a  = fmaf(v.z, wxc[4*qq+2], a);
      b2 = fmaf(v.w, wxc[4*qq+3], b2);
    }
    float v  = a + b2;
    float pv = dppf<DPP_X1>(v);               // partner gate's value
    float lo = (l & 1) ? pv : v;
    float hi = (l & 1) ? v  : pv;
    union { _Float16 h2[2]; unsigned u; } pk;
    pk.h2[0] = (_Float16)lo;
    pk.h2[1] = (_Float16)hi;
    zx[(size_t)row * 16 + (l >> 1)] = pk.u;   // aligned dword, 64B/row contiguous
  }
}

// ---------- Phase 2: recurrence, 8 lanes per batch (round-2 structure) ----------
__global__ __launch_bounds__(64, 2) void lstm_kernel(const __half* __restrict__ zx,
                                                     const float* __restrict__ h0,
                                                     const float* __restrict__ c0,
                                                     const float* __restrict__ Wh,
                                                     float* __restrict__ out) {
  int lane = (int)threadIdx.x;          // 0..63
  int b = blockIdx.x * 8 + (lane >> 3); // batch
  int s = lane & 7;                     // hidden unit

  // gather-register m holds h[s ^ XM[m]] after the DPP sequence
  constexpr int XM[8] = {0, 1, 2, 3, 7, 6, 5, 4};
  float wcf[8][4];
#pragma unroll
  for (int m = 0; m < 8; ++m) {
    int rowj = s ^ XM[m];
#pragma unroll
    for (int g = 0; g < 4; ++g) wcf[m][g] = Wh[rowj * 32 + g * 8 + s];
  }
#pragma unroll
  for (int m = 0; m < 8; ++m)
#pragma unroll
    for (int g = 0; g < 4; ++g) PIN(wcf[m][g]);

  float h = h0[b * 8 + s];
  float c = c0[b * 8 + s];

  const half4* zcur = (const half4*)zx + (size_t)b * T_STEPS * 8 + s;
  float*       ocur = out + (size_t)b * T_STEPS * 8 + s;

  constexpr int PD = 8;  // prefetch ring (statically indexed)
  half4 buf[PD];
#pragma unroll
  for (int p = 0; p < PD; ++p) buf[p] = zcur[(size_t)p * 8];

#define STEP(pp, PREFETCH)                                                   \
  {                                                                          \
    float2 zif = __half22float2(buf[pp].lo);                                 \
    float2 zgo = __half22float2(buf[pp].hi);                                 \
    if (PREFETCH) buf[pp] = zcur[(pp + PD) * 8];                             \
    float r0 = h;                                                            \
    float r1 = dppf<DPP_X1>(r0);                                             \
    float r2 = dppf<DPP_X2>(r0);                                             \
    float r3 = dppf<DPP_X2>(r1);                                             \
    float r4 = dppf<DPP_MIR8>(r0);                                           \
    float r5 = dppf<DPP_MIR8>(r1);                                           \
    float r6 = dppf<DPP_MIR8>(r2);                                           \
    float r7 = dppf<DPP_MIR8>(r3);                                           \
    float rr[8] = {r0, r1, r2, r3, r4, r5, r6, r7};                          \
    float za[4] = {zif.x, zif.y, zgo.x, zgo.y};                              \
    float aA[4], aB[4];                                                      \
    _Pragma("unroll") for (int g = 0; g < 4; ++g) {                          \
      aA[g] = fmaf(rr[0], wcf[0][g], za[g]);                                 \
      aB[g] = rr[4] * wcf[4][g];                                             \
    }                                                                        \
    _Pragma("unroll") for (int m = 1; m < 4; ++m) {                          \
      _Pragma("unroll") for (int g = 0; g < 4; ++g) {                        \
        aA[g] = fmaf(rr[m],     wcf[m][g],     aA[g]);                       \
        aB[g] = fmaf(rr[m + 4], wcf[m + 4][g], aB[g]);                       \
      }                                                                      \
    }                                                                        \
    float iv = frcp(1.0f + fexp2(-1.442695040888963f * (aA[0] + aB[0])));    \
    float fv = frcp(1.0f + fexp2(-1.442695040888963f * (aA[1] + aB[1])));    \
    float gv = fmaf(2.0f, frcp(1.0f + fexp2(-2.885390081777927f *            \
                                            (aA[2] + aB[2]))), -1.0f);       \
    float ov = frcp(1.0f + fexp2(-1.442695040888963f * (aA[3] + aB[3])));    \
    c = fmaf(fv, c, iv * gv);                                                \
    float th = fmaf(2.0f, frcp(1.0f + fexp2(-2.885390081777927f * c)), -1.0f);\
    h = ov * th;                                                             \
    ocur[pp * 8] = h;                                                        \
  }

  for (int tb = 0; tb < T_STEPS - PD; tb += PD) {
    STEP(0, true) STEP(1, true) STEP(2, true) STEP(3, true)
    STEP(4, true) STEP(5, true) STEP(6, true) STEP(7, true)
    zcur += PD * 8;
    ocur += PD * 8;
  }
  // epilogue: last PD steps, no prefetch
  STEP(0, false) STEP(1, false) STEP(2, false) STEP(3, false)
  STEP(4, false) STEP(5, false) STEP(6, false) STEP(7, false)
#undef STEP

  out[(size_t)BATCH * T_STEPS * 8 +             b * 8 + s] = h;
  out[(size_t)BATCH * T_STEPS * 8 + BATCH * 8 + b * 8 + s] = c;
}

extern "C" void kernel_launch(void* const* d_in, const int* in_sizes, int n_in,
                              void* d_out, int out_size, void* d_ws, size_t ws_size,
                              hipStream_t stream) {
  const float* x    = (const float*)d_in[0];
  const float* h0   = (const float*)d_in[1];
  const float* c0   = (const float*)d_in[2];
  const float* Wx   = (const float*)d_in[3];
  const float* Wh   = (const float*)d_in[4];
  const float* bias = (const float*)d_in[5];
  float* out = (float*)d_out;

  zx_kernel<<<2048, 256, 0, stream>>>(x, Wx, bias, (unsigned*)d_ws);
  lstm_kernel<<<BATCH / 8, 64, 0, stream>>>((const __half*)d_ws, h0, c0, Wh, out);
}

// Round 5
// 421.016 us; speedup vs baseline: 1.8977x; 1.1522x over previous
//
#include <hip/hip_runtime.h>
#include <hip/hip_fp16.h>

#define T_STEPS 2048
#define BATCH   256

// ---------- fast math ----------
__device__ __forceinline__ float fexp2(float x) {
#if __has_builtin(__builtin_amdgcn_exp2f)
  return __builtin_amdgcn_exp2f(x);
#else
  return exp2f(x);
#endif
}
__device__ __forceinline__ float frcp(float x) {
#if __has_builtin(__builtin_amdgcn_rcpf)
  return __builtin_amdgcn_rcpf(x);
#else
  return 1.0f / x;
#endif
}

// DPP cross-lane move (codes validated by passing rounds 2-4)
template<int CTRL>
__device__ __forceinline__ float dppf(float x) {
  int i = __float_as_int(x);
  int r = __builtin_amdgcn_update_dpp(i, i, CTRL, 0xF, 0xF, false);
  return __int_as_float(r);
}
#define DPP_X1 0xB1   // quad_perm {1,0,3,2}: lane^1
#define DPP_X2 0x4E   // quad_perm {2,3,0,1}: lane^2
#define DPP_HM 0x141  // row_half_mirror:     lane^7
#define DPP_RM 0x140  // row_mirror:          lane^15

// loop-carried pin: value becomes the output of an opaque asm each iteration,
// so the allocator can NEITHER rematerialize NOR shorten its live range.
#define PIN(x) asm volatile("" : "+v"(x))

#define L2E 1.442695040888963f

// ---------- Phase 1: ZX[b][t][unit*4+gate] = x@Wx + b  (fp16, packed dword stores) ----------
// lane l (0..31) owns PERMUTED position l -> original col j = (l&3)*8 + (l>>2).
__global__ __launch_bounds__(256, 4) void zx_kernel(const float* __restrict__ x,
                                                    const float* __restrict__ Wx,
                                                    const float* __restrict__ bias,
                                                    unsigned* __restrict__ zx) {
  __shared__ float sWx[1024];
  __shared__ float sb[32];
  {
    int t = (int)threadIdx.x;
    for (int i = t; i < 1024; i += 256) sWx[i] = Wx[i];
    if (t < 32) sb[t] = bias[t];
  }
  __syncthreads();

  int wave = (blockIdx.x * 256 + (int)threadIdx.x) >> 6;  // 0..8191
  int lane = (int)threadIdx.x & 63;
  int l    = lane & 31;
  int r    = lane >> 5;
  int j    = (l & 3) * 8 + (l >> 2);

  float wxc[32];
#pragma unroll
  for (int d = 0; d < 32; ++d) wxc[d] = sWx[d * 32 + j];  // ds_read: non-rematable
  float bj = sb[j];

  int base = wave * 64;  // 64 rows per wave, 2 per iter (one per half-wave)

  for (int it = 0; it < 32; ++it) {
#pragma unroll
    for (int d = 0; d < 32; ++d) PIN(wxc[d]);
    PIN(bj);
    int row = base + (it << 1) + r;
    const float4* xr = (const float4*)(x + (size_t)row * 32);
    float a = bj, b2 = 0.0f;
#pragma unroll
    for (int qq = 0; qq < 8; ++qq) {
      float4 v = xr[qq];
      a  = fmaf(v.x, wxc[4*qq+0], a);
      b2 = fmaf(v.y, wxc[4*qq+1], b2);
      a  = fmaf(v.z, wxc[4*qq+2], a);
      b2 = fmaf(v.w, wxc[4*qq+3], b2);
    }
    float v  = a + b2;
    float pv = dppf<DPP_X1>(v);               // partner gate's value
    float lo = (l & 1) ? pv : v;
    float hi = (l & 1) ? v  : pv;
    union { _Float16 h2[2]; unsigned u; } pk;
    pk.h2[0] = (_Float16)lo;
    pk.h2[1] = (_Float16)hi;
    zx[(size_t)row * 16 + (l >> 1)] = pk.u;   // aligned dword, 64B/row contiguous
  }
}

// ---------- Phase 2: recurrence, 16 lanes per batch (round-3 validated math) ----------
// lane q = u*2 + p : unit u (0..7), gate-pair p (0 -> gates i,f ; 1 -> g,o).
// h replicated on the p-pair; each 16-lane group is one DPP row.
__global__ __launch_bounds__(64, 1) void lstm_kernel(const __half* __restrict__ zx,
                                                     const float* __restrict__ h0,
                                                     const float* __restrict__ c0,
                                                     const float* __restrict__ Wh,
                                                     float* __restrict__ out) {
  __shared__ float sWh[256];
  int lane = (int)threadIdx.x;  // 0..63
  for (int i = lane; i < 256; i += 64) sWh[i] = Wh[i];
  __syncthreads();

  int b = blockIdx.x * 4 + (lane >> 4);   // 4 batches per wave
  int q = lane & 15;
  int u = q >> 1;
  int p = q & 1;
  bool pb = (p != 0);

  // weights pre-permuted so rr[m] pairs with h[u^m]; sourced from LDS (non-rematable)
  float wA[8], wB[8];
#pragma unroll
  for (int m = 0; m < 8; ++m) {
    int jrow = u ^ m;
    wA[m] = sWh[jrow * 32 + (2 * p) * 8 + u];
    wB[m] = sWh[jrow * 32 + (2 * p + 1) * 8 + u];
  }
  float cAc = pb ? -2.0f * L2E : -L2E;   // slot A: sigmoid (p=0,i) or tanh (p=1,g)
  float aAc = pb ? 2.0f : 1.0f;
  float bAc = pb ? -1.0f : 0.0f;

  float h = h0[b * 8 + u];
  float c = c0[b * 8 + u];

  const unsigned* zcur = (const unsigned*)zx + (size_t)b * T_STEPS * 16 + u * 2 + p;
  float*          ocur = out + (size_t)b * T_STEPS * 8 + u;

  constexpr int PD = 8;  // prefetch ring (statically indexed)
  unsigned buf[PD];
#pragma unroll
  for (int pp = 0; pp < PD; ++pp) buf[pp] = zcur[pp * 16];

#define STEP(pp, PRE)                                                        \
  {                                                                          \
    union { unsigned u32; __half2 h2; } zz; zz.u32 = buf[pp];                \
    float2 zf = __half22float2(zz.h2);  /* .x gate 2p, .y gate 2p+1 */       \
    if (PRE) buf[pp] = zcur[(pp + PD) * 16];                                 \
    float r0 = h;                       /* u     (depth 0) */                \
    float r1 = dppf<DPP_X2>(r0);        /* u^1   (depth 1) */                \
    float r3 = dppf<DPP_HM>(r0);        /* u^3   (depth 1) */                \
    float r7 = dppf<DPP_RM>(r0);        /* u^7   (depth 1) */                \
    float r2 = dppf<DPP_X2>(r3);        /* u^2   (depth 2) */                \
    float r6 = dppf<DPP_X2>(r7);        /* u^6   (depth 2) */                \
    float r4 = dppf<DPP_HM>(r7);        /* u^4   (depth 2) */                \
    float r5 = dppf<DPP_X2>(r4);        /* u^5   (depth 3) */                \
    float A0 = fmaf(r0, wA[0], zf.x);   /* chains ordered by availability */ \
    float B0 = fmaf(r0, wB[0], zf.y);                                        \
    float A1 = r1 * wA[1];                                                   \
    float B1 = r1 * wB[1];                                                   \
    A1 = fmaf(r3, wA[3], A1);  B1 = fmaf(r3, wB[3], B1);                     \
    A0 = fmaf(r2, wA[2], A0);  B0 = fmaf(r2, wB[2], B0);                     \
    A1 = fmaf(r7, wA[7], A1);  B1 = fmaf(r7, wB[7], B1);                     \
    A0 = fmaf(r6, wA[6], A0);  B0 = fmaf(r6, wB[6], B0);                     \
    A0 = fmaf(r4, wA[4], A0);  B0 = fmaf(r4, wB[4], B0);                     \
    A1 = fmaf(r5, wA[5], A1);  B1 = fmaf(r5, wB[5], B1);                     \
    float A = A0 + A1, B = B0 + B1;                                          \
    float Aact = fmaf(aAc, frcp(1.0f + fexp2(cAc * A)), bAc);                \
    float Bact = frcp(1.0f + fexp2(-L2E * B));                               \
    float A2 = dppf<DPP_X1>(Aact);                                           \
    float B2 = dppf<DPP_X1>(Bact);                                           \
    float iv = pb ? A2   : Aact;                                             \
    float fv = pb ? B2   : Bact;                                             \
    float gv = pb ? Aact : A2;                                               \
    float ov = pb ? Bact : B2;                                               \
    c = fmaf(fv, c, iv * gv);                                                \
    float th = fmaf(2.0f, frcp(1.0f + fexp2(-2.0f * L2E * c)), -1.0f);       \
    h = ov * th;                                                             \
    ocur[pp * 8] = h;   /* p-pair writes same addr/value (benign) */         \
  }

  for (int tb = 0; tb < T_STEPS - PD; tb += PD) {
    // loop-carried pins: weights cannot be rematerialized or dropped
#pragma unroll
    for (int m = 0; m < 8; ++m) { PIN(wA[m]); PIN(wB[m]); }
    PIN(cAc); PIN(aAc); PIN(bAc);
    STEP(0, 1) STEP(1, 1) STEP(2, 1) STEP(3, 1)
    STEP(4, 1) STEP(5, 1) STEP(6, 1) STEP(7, 1)
    zcur += PD * 16;
    ocur += PD * 8;
  }
  STEP(0, 0) STEP(1, 0) STEP(2, 0) STEP(3, 0)
  STEP(4, 0) STEP(5, 0) STEP(6, 0) STEP(7, 0)
#undef STEP

  out[(size_t)BATCH * T_STEPS * 8 +             b * 8 + u] = h;
  out[(size_t)BATCH * T_STEPS * 8 + BATCH * 8 + b * 8 + u] = c;
}

extern "C" void kernel_launch(void* const* d_in, const int* in_sizes, int n_in,
                              void* d_out, int out_size, void* d_ws, size_t ws_size,
                              hipStream_t stream) {
  const float* x    = (const float*)d_in[0];
  const float* h0   = (const float*)d_in[1];
  const float* c0   = (const float*)d_in[2];
  const float* Wx   = (const float*)d_in[3];
  const float* Wh   = (const float*)d_in[4];
  const float* bias = (const float*)d_in[5];
  float* out = (float*)d_out;

  zx_kernel<<<2048, 256, 0, stream>>>(x, Wx, bias, (unsigned*)d_ws);
  lstm_kernel<<<BATCH / 4, 64, 0, stream>>>((const __half*)d_ws, h0, c0, Wh, out);
}

// Round 9
// 401.471 us; speedup vs baseline: 1.9901x; 1.0487x over previous
//
#include <hip/hip_runtime.h>
#include <hip/hip_fp16.h>

#define T_STEPS 2048
#define BATCH   256

// ---------- DPP helper for zx kernel (validated rounds 2-5) ----------
template<int CTRL>
__device__ __forceinline__ float dppf(float x) {
  int i = __float_as_int(x);
  int r = __builtin_amdgcn_update_dpp(i, i, CTRL, 0xF, 0xF, false);
  return __int_as_float(r);
}
#define DPP_X1 0xB1   // quad_perm {1,0,3,2}: lane^1
#define PIN(x) asm volatile("" : "+v"(x))
#define L2E 1.442695040888963f

// ---------- Phase 1: ZX[b][t][unit*4+gate] = x@Wx + b (fp16, packed dword stores) ----------
// (unchanged from round 5 — validated)
__global__ __launch_bounds__(256, 4) void zx_kernel(const float* __restrict__ x,
                                                    const float* __restrict__ Wx,
                                                    const float* __restrict__ bias,
                                                    unsigned* __restrict__ zx) {
  __shared__ float sWx[1024];
  __shared__ float sb[32];
  {
    int t = (int)threadIdx.x;
    for (int i = t; i < 1024; i += 256) sWx[i] = Wx[i];
    if (t < 32) sb[t] = bias[t];
  }
  __syncthreads();

  int wave = (blockIdx.x * 256 + (int)threadIdx.x) >> 6;
  int lane = (int)threadIdx.x & 63;
  int l    = lane & 31;
  int r    = lane >> 5;
  int j    = (l & 3) * 8 + (l >> 2);

  float wxc[32];
#pragma unroll
  for (int d = 0; d < 32; ++d) wxc[d] = sWx[d * 32 + j];
  float bj = sb[j];

  int base = wave * 64;
  for (int it = 0; it < 32; ++it) {
#pragma unroll
    for (int d = 0; d < 32; ++d) PIN(wxc[d]);
    PIN(bj);
    int row = base + (it << 1) + r;
    const float4* xr = (const float4*)(x + (size_t)row * 32);
    float a = bj, b2 = 0.0f;
#pragma unroll
    for (int qq = 0; qq < 8; ++qq) {
      float4 v = xr[qq];
      a  = fmaf(v.x, wxc[4*qq+0], a);
      b2 = fmaf(v.y, wxc[4*qq+1], b2);
      a  = fmaf(v.z, wxc[4*qq+2], a);
      b2 = fmaf(v.w, wxc[4*qq+3], b2);
    }
    float v  = a + b2;
    float pv = dppf<DPP_X1>(v);
    float lo = (l & 1) ? pv : v;
    float hi = (l & 1) ? v  : pv;
    union { _Float16 h2[2]; unsigned u; } pk;
    pk.h2[0] = (_Float16)lo;
    pk.h2[1] = (_Float16)hi;
    zx[(size_t)row * 16 + (l >> 1)] = pk.u;
  }
}

// ---------- Phase 2: hand-scheduled asm recurrence, 16 lanes per batch ----------
// lane q=u*2+p; p=0 -> gates (i,f), p=1 -> (g,o). h replicated on p-pair.
// Gather mapping (validated r3/r5): quad_perm[2,3,0,1]->u^1, row_half_mirror->u^3,
// row_mirror->u^7 (p-flips harmless: h pair-replicated). wA/wB pre-permuted to match.

#define GATHER_DOTS \
  "v_mov_b32_dpp %[tC], %[h] quad_perm:[2,3,0,1] row_mask:0xf bank_mask:0xf\n\t" \
  "v_mov_b32_dpp %[tD], %[h] row_half_mirror row_mask:0xf bank_mask:0xf\n\t" \
  "v_mov_b32_dpp %[tE], %[h] row_mirror row_mask:0xf bank_mask:0xf\n\t" \
  "v_fmac_f32 %[tA], %[h], %[wA0]\n\t" \
  "v_fmac_f32 %[tB], %[h], %[wB0]\n\t" \
  "v_mov_b32_dpp %[tF], %[tD] quad_perm:[2,3,0,1] row_mask:0xf bank_mask:0xf\n\t" \
  "v_mul_f32 %[tG], %[tC], %[wA1]\n\t" \
  "v_mul_f32 %[tH], %[tC], %[wB1]\n\t" \
  "v_mov_b32_dpp %[tC], %[tE] quad_perm:[2,3,0,1] row_mask:0xf bank_mask:0xf\n\t" \
  "v_fmac_f32 %[tG], %[tD], %[wA3]\n\t" \
  "v_fmac_f32 %[tH], %[tD], %[wB3]\n\t" \
  "v_mov_b32_dpp %[tD], %[tE] row_half_mirror row_mask:0xf bank_mask:0xf\n\t" \
  "v_fmac_f32 %[tA], %[tF], %[wA2]\n\t" \
  "v_fmac_f32 %[tB], %[tF], %[wB2]\n\t" \
  "v_fmac_f32 %[tG], %[tE], %[wA7]\n\t" \
  "v_fmac_f32 %[tH], %[tE], %[wB7]\n\t" \
  "v_mov_b32_dpp %[tE], %[tD] quad_perm:[2,3,0,1] row_mask:0xf bank_mask:0xf\n\t" \
  "v_fmac_f32 %[tA], %[tC], %[wA6]\n\t" \
  "v_fmac_f32 %[tB], %[tC], %[wB6]\n\t" \
  "v_fmac_f32 %[tA], %[tD], %[wA4]\n\t" \
  "v_fmac_f32 %[tB], %[tD], %[wB4]\n\t" \
  "v_fmac_f32 %[tG], %[tE], %[wA5]\n\t" \
  "v_fmac_f32 %[tH], %[tE], %[wB5]\n\t"

#define ACTPART \
  "v_add_f32 %[tA], %[tA], %[tG]\n\t" \
  "v_add_f32 %[tB], %[tB], %[tH]\n\t" \
  "v_mul_f32 %[tC], %[cAc], %[tA]\n\t" \
  "v_mul_f32 %[tD], 0xbfb8aa3b, %[tB]\n\t" \
  "v_exp_f32 %[tC], %[tC]\n\t" \
  "v_exp_f32 %[tD], %[tD]\n\t" \
  "s_nop 0\n\t" \
  "v_add_f32 %[tC], 1.0, %[tC]\n\t" \
  "v_add_f32 %[tD], 1.0, %[tD]\n\t" \
  "v_rcp_f32 %[tC], %[tC]\n\t" \
  "v_rcp_f32 %[tD], %[tD]\n\t" \
  "s_nop 1\n\t" \
  "v_mov_b32_dpp %[tE], %[tD] quad_perm:[1,0,3,2] row_mask:0xf bank_mask:0xf\n\t" \
  "v_mov_b32_dpp %[tF], %[tC] quad_perm:[1,0,3,2] row_mask:0xf bank_mask:0xf\n\t" \
  "v_cndmask_b32 %[tG], %[tD], %[tE], vcc\n\t" \
  "v_cndmask_b32 %[tH], %[tE], %[tD], vcc\n\t" \
  "v_cndmask_b32 %[tE], %[tC], %[tF], vcc\n\t" \
  "v_mul_f32 %[tF], %[tC], %[tF]\n\t" \
  "v_fma_f32 %[tF], 2.0, %[tF], -%[tE]\n\t" \
  "v_fma_f32 %[c], %[tG], %[c], %[tF]\n\t" \
  "v_mul_f32 %[tA], 0xc038aa3b, %[c]\n\t" \
  "v_exp_f32 %[tA], %[tA]\n\t" \
  "s_nop 0\n\t" \
  "v_add_f32 %[tA], 1.0, %[tA]\n\t" \
  "v_rcp_f32 %[tA], %[tA]\n\t" \
  "s_nop 0\n\t" \
  "v_mul_f32 %[tB], %[tH], %[tA]\n\t" \
  "v_fma_f32 %[h], 2.0, %[tB], -%[tH]\n\t"

#define LSTEP(K, PF, SO) \
  "s_waitcnt vmcnt(7)\n\t" \
  "v_cvt_f32_f16 %[tA], %[b" #K "]\n\t" \
  "v_lshrrev_b32 %[tB], 16, %[b" #K "]\n\t" \
  "v_cvt_f32_f16 %[tB], %[tB]\n\t" \
  "global_load_dword %[b" #K "], %[zoff], %[zb] offset:" #PF "\n\t" \
  GATHER_DOTS ACTPART \
  "global_store_dword %[ooff], %[h], %[ob] offset:" #SO "\n\t"

#define ESTEP(K, SO) \
  "s_waitcnt vmcnt(7)\n\t" \
  "v_cvt_f32_f16 %[tA], %[b" #K "]\n\t" \
  "v_lshrrev_b32 %[tB], 16, %[b" #K "]\n\t" \
  "v_cvt_f32_f16 %[tB], %[tB]\n\t" \
  GATHER_DOTS ACTPART \
  "global_store_dword %[ooff], %[h], %[ob] offset:" #SO "\n\t"

__global__ __launch_bounds__(64, 1) void lstm_kernel(const __half* __restrict__ zx,
                                                     const float* __restrict__ h0,
                                                     const float* __restrict__ c0,
                                                     const float* __restrict__ Wh,
                                                     float* __restrict__ out) {
  __shared__ float sWh[256];
  int lane = (int)threadIdx.x;
  for (int i = lane; i < 256; i += 64) sWh[i] = Wh[i];
  __syncthreads();

  int b = blockIdx.x * 4 + (lane >> 4);
  int q = lane & 15;
  int u = q >> 1;
  int p = q & 1;

  float wA[8], wB[8];
#pragma unroll
  for (int m = 0; m < 8; ++m) {
    int jrow = u ^ m;
    wA[m] = sWh[jrow * 32 + (2 * p) * 8 + u];
    wB[m] = sWh[jrow * 32 + (2 * p + 1) * 8 + u];
  }
  float cAc = p ? (-2.0f * L2E) : (-L2E);

  float h = h0[b * 8 + u];
  float c = c0[b * 8 + u];

  const unsigned* zp = (const unsigned*)zx;
  unsigned zoff = (unsigned)(b * T_STEPS * 64 + u * 8 + p * 4);   // byte offset
  unsigned ooff = (unsigned)(b * T_STEPS * 32 + u * 4);           // byte offset

  unsigned b0 = zp[(zoff >> 2) + 0 * 16];
  unsigned b1 = zp[(zoff >> 2) + 1 * 16];
  unsigned b2 = zp[(zoff >> 2) + 2 * 16];
  unsigned b3 = zp[(zoff >> 2) + 3 * 16];
  unsigned b4 = zp[(zoff >> 2) + 4 * 16];
  unsigned b5 = zp[(zoff >> 2) + 5 * 16];
  unsigned b6 = zp[(zoff >> 2) + 6 * 16];
  unsigned b7 = zp[(zoff >> 2) + 7 * 16];

  float tA, tB, tC, tD, tE, tF, tG, tH;
  int cnt;

  asm volatile(
    // vcc = (lane & 1) == 1  (p-mask for cndmask selects)
    "v_mbcnt_lo_u32_b32 %[tA], -1, 0\n\t"
    "v_mbcnt_hi_u32_b32 %[tA], -1, %[tA]\n\t"
    "v_and_b32 %[tA], 1, %[tA]\n\t"
    "v_cmp_eq_u32 vcc, 1, %[tA]\n\t"
    "s_mov_b32 %[cnt], 255\n\t"
    "LSTM_LOOP%=:\n\t"
    LSTEP(0, 512, 0)
    LSTEP(1, 576, 32)
    LSTEP(2, 640, 64)
    LSTEP(3, 704, 96)
    LSTEP(4, 768, 128)
    LSTEP(5, 832, 160)
    LSTEP(6, 896, 192)
    LSTEP(7, 960, 224)
    "v_add_u32 %[zoff], 0x200, %[zoff]\n\t"
    "v_add_u32 %[ooff], 0x100, %[ooff]\n\t"
    "s_sub_u32 %[cnt], %[cnt], 1\n\t"
    "s_cmp_lg_u32 %[cnt], 0\n\t"
    "s_cbranch_scc1 LSTM_LOOP%=\n\t"
    // epilogue: last 8 steps, no prefetch
    ESTEP(0, 0)
    ESTEP(1, 32)
    ESTEP(2, 64)
    ESTEP(3, 96)
    ESTEP(4, 128)
    ESTEP(5, 160)
    ESTEP(6, 192)
    ESTEP(7, 224)
    : [h]"+v"(h), [c]"+v"(c), [zoff]"+v"(zoff), [ooff]"+v"(ooff),
      [b0]"+v"(b0), [b1]"+v"(b1), [b2]"+v"(b2), [b3]"+v"(b3),
      [b4]"+v"(b4), [b5]"+v"(b5), [b6]"+v"(b6), [b7]"+v"(b7),
      [tA]"=&v"(tA), [tB]"=&v"(tB), [tC]"=&v"(tC), [tD]"=&v"(tD),
      [tE]"=&v"(tE), [tF]"=&v"(tF), [tG]"=&v"(tG), [tH]"=&v"(tH),
      [cnt]"=&s"(cnt)
    : [wA0]"v"(wA[0]), [wA1]"v"(wA[1]), [wA2]"v"(wA[2]), [wA3]"v"(wA[3]),
      [wA4]"v"(wA[4]), [wA5]"v"(wA[5]), [wA6]"v"(wA[6]), [wA7]"v"(wA[7]),
      [wB0]"v"(wB[0]), [wB1]"v"(wB[1]), [wB2]"v"(wB[2]), [wB3]"v"(wB[3]),
      [wB4]"v"(wB[4]), [wB5]"v"(wB[5]), [wB6]"v"(wB[6]), [wB7]"v"(wB[7]),
      [cAc]"v"(cAc), [zb]"s"(zp), [ob]"s"(out)
    : "vcc", "scc", "memory");

  out[(size_t)BATCH * T_STEPS * 8 +             b * 8 + u] = h;
  out[(size_t)BATCH * T_STEPS * 8 + BATCH * 8 + b * 8 + u] = c;
}

extern "C" void kernel_launch(void* const* d_in, const int* in_sizes, int n_in,
                              void* d_out, int out_size, void* d_ws, size_t ws_size,
                              hipStream_t stream) {
  const float* x    = (const float*)d_in[0];
  const float* h0   = (const float*)d_in[1];
  const float* c0   = (const float*)d_in[2];
  const float* Wx   = (const float*)d_in[3];
  const float* Wh   = (const float*)d_in[4];
  const float* bias = (const float*)d_in[5];
  float* out = (float*)d_out;

  zx_kernel<<<2048, 256, 0, stream>>>(x, Wx, bias, (unsigned*)d_ws);
  lstm_kernel<<<BATCH / 4, 64, 0, stream>>>((const __half*)d_ws, h0, c0, Wh, out);
}